// Round 11
// baseline (446.848 us; speedup 1.0000x reference)
//
#include <hip/hip_runtime.h>
#include <hip/hip_cooperative_groups.h>
#include <math.h>

namespace cg = cooperative_groups;

// ---- fixed CT geometry (matches reference) ----
#define IMG    512
#define NPIX   (IMG * IMG)
#define NDET   768
#define NVIEWS 360
#define BATCH  2
#define PIX    0.7433f
#define DSO_F  595.0f
#define DSD_D  (595.0 + 490.6)
#define DGAMMA_D (1.2858 / DSD_D)
#define DGAMMA_F ((float)DGAMMA_D)

// workspace float-index layout
#define WS_G2    0        // [0,1536): gE[768] | gEs[768] (compacted odd ramp taps)
#define WS_G0    1536     // center tap
#define WS_TRIG  1538     // float2[360] (byte 6152, 8B aligned)
#define WS_QI    2304     // batch-interleaved sinogram [360][768][2]
#define QROWB    (NDET * 8)            // 6144 B per interleaved q row
#define QTOTB    (NVIEWS * QROWB)
#define CHUNKS   8
#define VPC      (NVIEWS / CHUNKS)     // 45 views per chunk
#define GRID     2048                  // = 256 CU x 8 blocks (coop co-resident)
#define FROWS    (BATCH * NVIEWS)      // 720 filter rows

// ---------------------------------------------------------------------------
// Phase 0: zero output (replaces memset node) + ramp/trig tables (f64->f32).
// GRID*256 threads == 2*NPIX exactly.
// ---------------------------------------------------------------------------
__device__ __forceinline__ void phase_init(int gtid, float* __restrict__ ws,
                                           float* __restrict__ out) {
    if (gtid < 2 * NPIX) out[gtid] = 0.0f;
    if (gtid < 768) {                         // gE[m] = g(2m-767), odd taps
        int n = 2 * gtid - 767;
        double s = M_PI * sin((double)n * DGAMMA_D);
        ws[WS_G2 + gtid] = (float)(-0.5 / (s * s));
    } else if (gtid < 1536) {                 // gEs[k] = gE[k+1] (aligned copy)
        int k = gtid - 768;
        if (k == 767) ws[WS_G2 + gtid] = 0.0f;
        else {
            int n = 2 * k - 765;
            double s = M_PI * sin((double)n * DGAMMA_D);
            ws[WS_G2 + gtid] = (float)(-0.5 / (s * s));
        }
    } else if (gtid == 1536) {
        ws[WS_G0] = (float)(1.0 / (8.0 * DGAMMA_D * DGAMMA_D));
    } else if (gtid >= 1600 && gtid < 1600 + NVIEWS) {
        int v = gtid - 1600;
        double b = (double)v * (2.0 * M_PI / (double)NVIEWS);
        ((float2*)(ws + WS_TRIG))[v] = make_float2((float)cos(b), (float)sin(b));
    }
}

// ---------------------------------------------------------------------------
// Phase 1: cosine weighting + compacted ramp convolution (zero even taps
// skipped; 385 real MACs/output). Output is BATCH-INTERLEAVED:
//   qI[v][i][b], so backprojection fetches both batches with one float2.
// Blocks 0..719 (block-uniform early-out), 192 conv lanes (96 even + 96 odd),
// register tile 4 outputs x 4 taps per 3 LDS float4 reads.
// ---------------------------------------------------------------------------
__device__ __forceinline__ void phase_filter(int bid, int tid,
        const float* __restrict__ proj, float* __restrict__ ws) {
    __shared__ __align__(16) float g2_s[1536];
    __shared__ __align__(16) float pE_s[384];
    __shared__ __align__(16) float pO_s[384];

    if (bid >= FROWS) return;                 // block-uniform: no sync hazard

    for (int i = tid; i < 384; i += 256)
        ((float4*)g2_s)[i] = ((const float4*)(ws + WS_G2))[i];
    const float g0 = ws[WS_G0];

    const int b = (bid >= NVIEWS) ? 1 : 0;
    const int v = bid - b * NVIEWS;
    const float* prow = proj + (size_t)bid * NDET;
    for (int j = tid; j < NDET; j += 256) {   // j parity == tid parity
        float gam = ((float)j - 383.5f) * DGAMMA_F;
        float val = prow[j] * (DSO_F * cosf(gam));
        if (j & 1) pO_s[j >> 1] = val; else pE_s[j >> 1] = val;
    }
    __syncthreads();

    if (tid >= 192) return;
    const int odd = (tid >= 96) ? 1 : 0;
    const int s   = odd ? tid - 96 : tid;
    const float* gbase = g2_s + (odd ? 768 : 0);
    const float* pbase = odd ? pE_s : pO_s;   // conv source (opposite parity)
    const float* cbase = odd ? pO_s : pE_s;   // center term (own parity)

    float a0 = 0.f, a1 = 0.f, a2 = 0.f, a3 = 0.f;
    #pragma unroll 4
    for (int beta = 0; beta < 96; ++beta) {
        const float4 p4 = *(const float4*)&pbase[4 * beta];
        const int W = 4 * s + 380 - 4 * beta;          // [0,760], 16B aligned
        const float4 ga = *(const float4*)&gbase[W];
        const float4 gb = *(const float4*)&gbase[W + 4];
        a0 = fmaf(p4.x, ga.w, a0); a0 = fmaf(p4.y, ga.z, a0);
        a0 = fmaf(p4.z, ga.y, a0); a0 = fmaf(p4.w, ga.x, a0);
        a1 = fmaf(p4.x, gb.x, a1); a1 = fmaf(p4.y, ga.w, a1);
        a1 = fmaf(p4.z, ga.z, a1); a1 = fmaf(p4.w, ga.y, a1);
        a2 = fmaf(p4.x, gb.y, a2); a2 = fmaf(p4.y, gb.x, a2);
        a2 = fmaf(p4.z, ga.w, a2); a2 = fmaf(p4.w, ga.z, a2);
        a3 = fmaf(p4.x, gb.z, a3); a3 = fmaf(p4.y, gb.y, a3);
        a3 = fmaf(p4.z, gb.x, a3); a3 = fmaf(p4.w, ga.w, a3);
    }

    // outputs i = 8s + 2d + odd -> interleaved float offset v*1536 + 2i + b
    float* qrow = ws + WS_QI + v * 1536 + 16 * s + 2 * odd + b;
    const float sc = DGAMMA_F;
    qrow[0]  = fmaf(g0, cbase[4 * s + 0], a0) * sc;
    qrow[4]  = fmaf(g0, cbase[4 * s + 1], a1) * sc;
    qrow[8]  = fmaf(g0, cbase[4 * s + 2], a2) * sc;
    qrow[12] = fmaf(g0, cbase[4 * s + 3], a3) * sc;
}

// ---------------------------------------------------------------------------
// Phase 2: quad-symmetric backprojection (round-10 math, gather-optimized).
//   A=(x,y)@v, B=(x,-y)@360-v, C=(-x,y)@180-v, D=(-x,-y)@180+v share
//   dot/|cross|/L2; B,C use exact mirror gidx_m = 383.5 - at/dg.
// Gather改: 16x16 pixel tiles (wave = 4x16 px -> ~38-bin gidx spread, ~2x
// fewer cache lines) + batch-interleaved q (8x float2 instead of 16x dword).
// gidx accuracy (round-4 lesson): deg-21 Taylor + Newton-refined rcp.
// ---------------------------------------------------------------------------
__device__ __forceinline__ void phase_backproject(int bid, int tid,
        const float* __restrict__ ws, float* __restrict__ out) {
    __shared__ float2 trig_s[VPC];

    const int chunk = bid & (CHUNKS - 1);
    const int pb    = bid >> 3;               // pixel tile id [0,256)
    if (tid < VPC)
        trig_s[tid] = ((const float2*)(ws + WS_TRIG))[chunk * VPC + tid];
    __syncthreads();

    const int tr = pb >> 4, tc = pb & 15;     // 16x16 tiles over the quadrant
    const int r  = tr * 16 + (tid >> 4);      // [0,256)
    const int cc = tc * 16 + (tid & 15);      // [0,256)
    const float x = ((float)cc - 255.5f) * PIX;   // negative quadrant
    const float y = ((float)r  - 255.5f) * PIX;
    const float inv_dg = (float)(1.0 / DGAMMA_D);

    const char* qc = (const char*)(ws + WS_QI);
    const int v0 = chunk * VPC;
    int oA = v0 * QROWB;
    int oB = ((NVIEWS - v0) % NVIEWS) * QROWB;
    int oC = ((((180 - v0) % NVIEWS) + NVIEWS) % NVIEWS) * QROWB;
    int oD = ((180 + v0) % NVIEWS) * QROWB;

    float aA0 = 0.f, aA1 = 0.f, aB0 = 0.f, aB1 = 0.f;
    float aC0 = 0.f, aC1 = 0.f, aD0 = 0.f, aD1 = 0.f;

    for (int i = 0; i < VPC; ++i) {
        const float2 cs = trig_s[i];
        const float cb = cs.x, sb = cs.y;
        const float dot   = fmaf(-sb, y, fmaf(-cb, x, DSO_F));  // >= 326
        const float cross = fmaf(-cb, y, sb * x);
        float rd = __builtin_amdgcn_rcpf(dot);
        rd = fmaf(rd, fmaf(-dot, rd, 1.0f), rd);                // Newton: ~ulp
        const float t = cross * rd;
        const float u = t * t;

        if (u <= 0.2704f) {
            float sp = fmaf(u, 0.04761905f, -0.05263158f);  //  1/21, -1/19
            sp = fmaf(u, sp,  0.05882353f);                 //  1/17
            sp = fmaf(u, sp, -0.06666667f);                 // -1/15
            sp = fmaf(u, sp,  0.07692308f);                 //  1/13
            sp = fmaf(u, sp, -0.09090909f);                 // -1/11
            sp = fmaf(u, sp,  0.11111111f);                 //  1/9
            sp = fmaf(u, sp, -0.14285715f);                 // -1/7
            sp = fmaf(u, sp,  0.20000000f);                 //  1/5
            sp = fmaf(u, sp, -0.33333334f);                 // -1/3
            const float at   = fmaf(t * u, sp, t);
            const float gidx = fmaf(at,  inv_dg, 383.5f);

            if (gidx >= 0.0f && gidx <= 767.0f) {
                const float gm = fmaf(at, -inv_dg, 383.5f);
                const int i0  = min((int)gidx, 766);
                const int i0m = min((int)gm,   766);
                const float w  = gidx - (float)i0;
                const float wm = gm   - (float)i0m;
                const float rl2 =
                    __builtin_amdgcn_rcpf(fmaf(dot, dot, cross * cross));

                const float2 A0 = *(const float2*)(qc + oA + (i0  << 3));
                const float2 A1 = *(const float2*)(qc + oA + (i0  << 3) + 8);
                const float2 B0 = *(const float2*)(qc + oB + (i0m << 3));
                const float2 B1 = *(const float2*)(qc + oB + (i0m << 3) + 8);
                const float2 C0 = *(const float2*)(qc + oC + (i0m << 3));
                const float2 C1 = *(const float2*)(qc + oC + (i0m << 3) + 8);
                const float2 D0 = *(const float2*)(qc + oD + (i0  << 3));
                const float2 D1 = *(const float2*)(qc + oD + (i0  << 3) + 8);

                aA0 = fmaf(fmaf(w,  A1.x - A0.x, A0.x), rl2, aA0);
                aA1 = fmaf(fmaf(w,  A1.y - A0.y, A0.y), rl2, aA1);
                aB0 = fmaf(fmaf(wm, B1.x - B0.x, B0.x), rl2, aB0);
                aB1 = fmaf(fmaf(wm, B1.y - B0.y, B0.y), rl2, aB1);
                aC0 = fmaf(fmaf(wm, C1.x - C0.x, C0.x), rl2, aC0);
                aC1 = fmaf(fmaf(wm, C1.y - C0.y, C0.y), rl2, aC1);
                aD0 = fmaf(fmaf(w,  D1.x - D0.x, D0.x), rl2, aD0);
                aD1 = fmaf(fmaf(w,  D1.y - D0.y, D0.y), rl2, aD1);
            }
        }

        oA += QROWB;
        oB -= QROWB; if (oB < 0) oB += QTOTB;
        oC -= QROWB; if (oC < 0) oC += QTOTB;
        oD += QROWB; if (oD >= QTOTB) oD -= QTOTB;
    }

    const float SCALE = (float)(2.0 * M_PI / (double)NVIEWS);
    const int rM = 511 - r, cM = 511 - cc;
    atomicAdd(&out[(r  << 9) + cc],         aA0 * SCALE);
    atomicAdd(&out[(rM << 9) + cc],         aB0 * SCALE);
    atomicAdd(&out[(r  << 9) + cM],         aC0 * SCALE);
    atomicAdd(&out[(rM << 9) + cM],         aD0 * SCALE);
    atomicAdd(&out[(r  << 9) + cc  + NPIX], aA1 * SCALE);
    atomicAdd(&out[(rM << 9) + cc  + NPIX], aB1 * SCALE);
    atomicAdd(&out[(r  << 9) + cM  + NPIX], aC1 * SCALE);
    atomicAdd(&out[(rM << 9) + cM  + NPIX], aD1 * SCALE);
}

// ---------------------------------------------------------------------------
// Fused cooperative kernel: 1 graph node instead of 4 (~10-15 us/node).
// 2048 blocks x 256 thr = 8 blocks/CU co-resident (launch_bounds caps
// VGPR<=64, LDS 9.6KB <= 20KB/block).
// ---------------------------------------------------------------------------
__global__ __launch_bounds__(256, 8) void fused_kernel(
        const float* __restrict__ proj, float* __restrict__ ws,
        float* __restrict__ out) {
    cg::grid_group grid = cg::this_grid();
    const int tid = threadIdx.x, bid = blockIdx.x;
    phase_init(bid * 256 + tid, ws, out);
    grid.sync();
    phase_filter(bid, tid, proj, ws);
    grid.sync();
    phase_backproject(bid, tid, ws, out);
}

// classic 3-node fallback (same phases) if cooperative launch is unsupported
__global__ void init_kernel_std(float* __restrict__ ws, float* __restrict__ out) {
    phase_init(blockIdx.x * 256 + threadIdx.x, ws, out);
}
__global__ __launch_bounds__(256) void filter_kernel_std(
        const float* __restrict__ proj, float* __restrict__ ws) {
    phase_filter(blockIdx.x, threadIdx.x, proj, ws);
}
__global__ __launch_bounds__(256) void backproject_kernel_std(
        const float* __restrict__ ws, float* __restrict__ out) {
    phase_backproject(blockIdx.x, threadIdx.x, ws, out);
}

// ---------------------------------------------------------------------------
extern "C" void kernel_launch(void* const* d_in, const int* in_sizes, int n_in,
                              void* d_out, int out_size, void* d_ws, size_t ws_size,
                              hipStream_t stream) {
    const float* proj = (const float*)d_in[0];   // [2, 360, 768] f32
    float* out = (float*)d_out;                  // [2, 512, 512] f32
    float* ws  = (float*)d_ws;

    void* args[] = { (void*)&proj, (void*)&ws, (void*)&out };
    hipError_t rc = hipLaunchCooperativeKernel((const void*)fused_kernel,
                        dim3(GRID), dim3(256), args, 0, stream);
    if (rc != hipSuccess) {
        (void)hipGetLastError();                 // clear, use classic path
        init_kernel_std<<<GRID, 256, 0, stream>>>(ws, out);
        filter_kernel_std<<<FROWS, 256, 0, stream>>>(proj, ws);
        backproject_kernel_std<<<GRID, 256, 0, stream>>>(ws, out);
    }
}